// Round 8
// baseline (197.217 us; speedup 1.0000x reference)
//
#include <hip/hip_runtime.h>
#include <hip/hip_fp16.h>
#include <math.h>

#define N_NODES   50000
#define N_EDGES   800000
#define N_FEAT    128
#define HIDDEN    64
#define EMBED     300
#define N_CLASSES 10
#define N_GRAPHS  500
#define LEAKY     0.01f
#define SCAN_BLOCKS ((N_NODES + 255) / 256)  // 196
#define G1_ROWS   32

typedef __attribute__((ext_vector_type(8))) _Float16 half8f;

// packed edge: low 16 bits = src node id (50000 < 65536), high 16 = fp16 norm
__device__ __forceinline__ float pk_w(unsigned p) {
    return __half2float(__ushort_as_half((unsigned short)(p >> 16)));
}

// ---------------- init ----------------
__global__ void k_zero(int* deg, int* gs, int* ge) {
    int i = blockIdx.x * 256 + threadIdx.x;
    if (i < N_NODES) deg[i] = 0;
    if (i < N_GRAPHS) { gs[i] = 0; ge[i] = 0; }
}

// ---------------- degree count + per-edge rank (coalesced rank write) ----------------
__global__ void k_deg_rank(const int* __restrict__ dst, int* deg, int* rank) {
    int e = blockIdx.x * 256 + threadIdx.x;
    if (e < N_EDGES) rank[e] = atomicAdd(&deg[dst[e]], 1);
}

// ---------------- scan: deg -> row_start (exclusive); dis = rsqrt(deg+1) ----------------
__global__ __launch_bounds__(256) void k_scan1(const int* __restrict__ deg, int* row_start,
                                               int* partials, float* dis) {
    __shared__ int wsum[4];
    int i = blockIdx.x * 256 + threadIdx.x;
    int v = (i < N_NODES) ? deg[i] : 0;
    int lane = threadIdx.x & 63, wid = threadIdx.x >> 6;
    int s = v;
    #pragma unroll
    for (int off = 1; off < 64; off <<= 1) {
        int t = __shfl_up(s, off, 64);
        if (lane >= off) s += t;
    }
    if (lane == 63) wsum[wid] = s;
    __syncthreads();
    int woff = 0;
    for (int w = 0; w < wid; ++w) woff += wsum[w];
    if (i < N_NODES) {
        row_start[i] = woff + s - v;
        dis[i] = rsqrtf((float)(deg[i] + 1));
    }
    if (threadIdx.x == 255) partials[blockIdx.x] = woff + s;
}

__global__ __launch_bounds__(256) void k_scan2(int* partials) {
    __shared__ int wsum[4];
    int v = (threadIdx.x < SCAN_BLOCKS) ? partials[threadIdx.x] : 0;
    int lane = threadIdx.x & 63, wid = threadIdx.x >> 6;
    int s = v;
    #pragma unroll
    for (int off = 1; off < 64; off <<= 1) {
        int t = __shfl_up(s, off, 64);
        if (lane >= off) s += t;
    }
    if (lane == 63) wsum[wid] = s;
    __syncthreads();
    int woff = 0;
    for (int w = 0; w < wid; ++w) woff += wsum[w];
    if (threadIdx.x < SCAN_BLOCKS) partials[threadIdx.x] = woff + s - v;
}

__global__ void k_scan3(int* row_start, const int* __restrict__ partials) {
    int i = blockIdx.x * 256 + threadIdx.x;
    if (i < N_NODES) row_start[i] += partials[blockIdx.x];
    if (i == 0) row_start[N_NODES] = N_EDGES;
}

// ---------------- CSR fill: one packed 4B scatter per edge ----------------
__global__ void k_fill(const int* __restrict__ src, const int* __restrict__ dst,
                       const int* __restrict__ rank, const int* __restrict__ row_start,
                       const float* __restrict__ dis, unsigned* __restrict__ pk) {
    int e = blockIdx.x * 256 + threadIdx.x;
    if (e < N_EDGES) {
        int s = src[e], d = dst[e];
        float w = dis[s] * dis[d];
        unsigned short wh = __half_as_ushort(__float2half(w));
        pk[row_start[d] + rank[e]] = (unsigned)s | ((unsigned)wh << 16);
    }
}

// ---------------- GEMM1: h1 = x @ W1 (fp16 out), 32 rows/block ----------------
__global__ __launch_bounds__(256) void k_gemm1(const float* __restrict__ x,
                                               const float* __restrict__ W,
                                               __half* __restrict__ h) {
    __shared__ float sW[N_FEAT * HIDDEN];   // 32 KB
    __shared__ float sx[G1_ROWS * N_FEAT];  // 16 KB
    {
        const float4* W4 = (const float4*)W;
        float4* sW4 = (float4*)sW;
        #pragma unroll
        for (int i = 0; i < N_FEAT * HIDDEN / 4 / 256; ++i)
            sW4[i * 256 + threadIdx.x] = W4[i * 256 + threadIdx.x];

        int base = blockIdx.x * G1_ROWS;
        const float4* x4 = (const float4*)(x + (size_t)base * N_FEAT);
        float4* sx4 = (float4*)sx;
        int lim = (N_NODES - base) * (N_FEAT / 4);
        #pragma unroll
        for (int i = 0; i < G1_ROWS * N_FEAT / 4 / 256; ++i) {
            int idx = i * 256 + threadIdx.x;
            sx4[idx] = (idx < lim) ? x4[idx] : make_float4(0.f, 0.f, 0.f, 0.f);
        }
    }
    __syncthreads();

    int f = threadIdx.x & 63, wid = threadIdx.x >> 6;
    float acc[8];
    #pragma unroll
    for (int u = 0; u < 8; ++u) acc[u] = 0.0f;

    const float4* sx4 = (const float4*)sx;
    #pragma unroll 4
    for (int k4 = 0; k4 < N_FEAT / 4; ++k4) {
        float w0 = sW[(k4 * 4 + 0) * HIDDEN + f];
        float w1 = sW[(k4 * 4 + 1) * HIDDEN + f];
        float w2 = sW[(k4 * 4 + 2) * HIDDEN + f];
        float w3 = sW[(k4 * 4 + 3) * HIDDEN + f];
        #pragma unroll
        for (int u = 0; u < 8; ++u) {
            float4 xv = sx4[(wid * 8 + u) * (N_FEAT / 4) + k4];
            acc[u] = fmaf(xv.x, w0, fmaf(xv.y, w1, fmaf(xv.z, w2, fmaf(xv.w, w3, acc[u]))));
        }
    }
    int base = blockIdx.x * G1_ROWS;
    #pragma unroll
    for (int u = 0; u < 8; ++u) {
        int n = base + wid * 8 + u;
        if (n < N_NODES) h[(size_t)n * HIDDEN + f] = __float2half(acc[u]);
    }
}

// ---------------- gather core: 8 edges/instr (8 lanes x 16B), preloaded pk chunk ----------------
// lane = [g8 = edge slot (lane>>3)][q8 = feature octet (lane&7)]
// pv: preloaded pk[s + lane] for the first 64-edge chunk (0 if OOB).
__device__ __forceinline__ void gather8_node(const __half* __restrict__ h,
                                             const unsigned* __restrict__ pk,
                                             int s, int e, unsigned pv,
                                             int lane, int g8, int q8, float acc[8]) {
    int cs = s;
    while (cs < e) {
        int avail = e - cs; if (avail > 64) avail = 64;
        int iters = (avail + 7) >> 3;
        #pragma unroll 2
        for (int t = 0; t < iters; ++t) {
            unsigned p = __shfl(pv, t * 8 + g8, 64);   // w=0 for padded slots
            float w = pk_w(p);
            half8f hv = *(const half8f*)(h + ((size_t)(p & 0xFFFFu)) * HIDDEN + (q8 << 3));
            #pragma unroll
            for (int c = 0; c < 8; ++c) acc[c] = fmaf(w, (float)hv[c], acc[c]);
        }
        cs += 64;
        if (cs < e) pv = (cs + lane < e) ? pk[cs + lane] : 0u;
    }
}

__device__ __forceinline__ void xreduce8(float a[8]) {
    #pragma unroll
    for (int m = 8; m < 64; m <<= 1) {
        #pragma unroll
        for (int c = 0; c < 8; ++c) a[c] += __shfl_xor(a[c], m, 64);
    }
}

// r[c] = relu(self*dd + b[c] + acc[c]) for this lane's feature octet
__device__ __forceinline__ void finish8(const __half* __restrict__ h, int node,
                                        const float* __restrict__ b, float dd,
                                        int q8, const float acc[8], float r[8]) {
    half8f sv = *(const half8f*)(h + (size_t)node * HIDDEN + (q8 << 3));
    #pragma unroll
    for (int c = 0; c < 8; ++c)
        r[c] = fmaxf(fmaf((float)sv[c], dd, b[(q8 << 3) + c]) + acc[c], 0.f);
}

// ---------------- fused conv1-gather + gemm2, 16 nodes/block ----------------
__global__ __launch_bounds__(256) void k_gg(const __half* __restrict__ h1,
                                            const unsigned* __restrict__ pk,
                                            const int* __restrict__ row_start,
                                            const float* __restrict__ dis,
                                            const float* __restrict__ b1,
                                            const float* __restrict__ W2,
                                            __half* __restrict__ h2) {
    __shared__ float sW[HIDDEN * HIDDEN];  // 16 KB
    __shared__ float sa[16 * HIDDEN];      // 4 KB
    {
        const float4* W4 = (const float4*)W2;
        float4* sW4 = (float4*)sW;
        #pragma unroll
        for (int i = 0; i < 4; ++i)
            sW4[i * 256 + threadIdx.x] = W4[i * 256 + threadIdx.x];
    }

    int tid = threadIdx.x, wid = tid >> 6, lane = tid & 63;
    int g8 = lane >> 3, q8 = lane & 7;
    int base = blockIdx.x * 16 + wid * 4;   // grid exact: 50000 = 3125*16

    // row bounds for 4 nodes (contiguous)
    int r0 = row_start[base + 0], r1 = row_start[base + 1];
    int r2 = row_start[base + 2], r3 = row_start[base + 3];
    int r4 = row_start[base + 4];

    // pre-issue all 4 first-chunk pk loads (independent, in flight together)
    unsigned pv0 = (r0 + lane < r1) ? pk[r0 + lane] : 0u;
    unsigned pv1 = (r1 + lane < r2) ? pk[r1 + lane] : 0u;
    unsigned pv2 = (r2 + lane < r3) ? pk[r2 + lane] : 0u;
    unsigned pv3 = (r3 + lane < r4) ? pk[r3 + lane] : 0u;

    float a0[8] = {0,0,0,0,0,0,0,0}, a1[8] = {0,0,0,0,0,0,0,0};
    float a2[8] = {0,0,0,0,0,0,0,0}, a3[8] = {0,0,0,0,0,0,0,0};
    gather8_node(h1, pk, r0, r1, pv0, lane, g8, q8, a0);
    gather8_node(h1, pk, r1, r2, pv1, lane, g8, q8, a1);
    gather8_node(h1, pk, r2, r3, pv2, lane, g8, q8, a2);
    gather8_node(h1, pk, r3, r4, pv3, lane, g8, q8, a3);
    xreduce8(a0); xreduce8(a1); xreduce8(a2); xreduce8(a3);

    #pragma unroll
    for (int i = 0; i < 4; ++i) {
        const float* ai = (i == 0) ? a0 : (i == 1) ? a1 : (i == 2) ? a2 : a3;
        int node = base + i;
        float dv = dis[node], dd = dv * dv;
        float r[8];
        finish8(h1, node, b1, dd, q8, ai, r);
        if (g8 == 0) {
            float* dstp = &sa[(wid * 4 + i) * HIDDEN + (q8 << 3)];
            *(float4*)dstp = make_float4(r[0], r[1], r[2], r[3]);
            *(float4*)(dstp + 4) = make_float4(r[4], r[5], r[6], r[7]);
        }
    }
    __syncthreads();

    // joint 4-node matvec: one sW read feeds 4 FMAs
    int f = lane;
    float o0 = 0.f, o1 = 0.f, o2 = 0.f, o3 = 0.f;
    const float* sa0 = &sa[wid * 4 * HIDDEN];
    #pragma unroll 8
    for (int k = 0; k < HIDDEN; ++k) {
        float wv = sW[k * HIDDEN + f];
        o0 = fmaf(sa0[k], wv, o0);
        o1 = fmaf(sa0[HIDDEN + k], wv, o1);
        o2 = fmaf(sa0[2 * HIDDEN + k], wv, o2);
        o3 = fmaf(sa0[3 * HIDDEN + k], wv, o3);
    }
    h2[(size_t)(base + 0) * HIDDEN + f] = __float2half(o0);
    h2[(size_t)(base + 1) * HIDDEN + f] = __float2half(o1);
    h2[(size_t)(base + 2) * HIDDEN + f] = __float2half(o2);
    h2[(size_t)(base + 3) * HIDDEN + f] = __float2half(o3);
}

// ---------------- conv2-gather + fused attention score, 1 node/wave ----------------
__global__ __launch_bounds__(256) void k_gather2(const __half* __restrict__ h2,
                                                 const unsigned* __restrict__ pk,
                                                 const int* __restrict__ row_start,
                                                 const float* __restrict__ dis,
                                                 const float* __restrict__ b2,
                                                 const float* __restrict__ att_w,
                                                 const float* __restrict__ att_b,
                                                 float* __restrict__ agg2,
                                                 float* __restrict__ att_s) {
    int tid = threadIdx.x, wid = tid >> 6, lane = tid & 63;
    int g8 = lane >> 3, q8 = lane & 7;
    int node = blockIdx.x * 4 + wid;   // grid exact: 12500*4 = 50000
    int s = row_start[node], e = row_start[node + 1];
    unsigned pv = (s + lane < e) ? pk[s + lane] : 0u;
    float acc[8] = {0,0,0,0,0,0,0,0};
    gather8_node(h2, pk, s, e, pv, lane, g8, q8, acc);
    xreduce8(acc);
    float dv = dis[node], dd = dv * dv;
    float r[8];
    finish8(h2, node, b2, dd, q8, acc, r);
    if (g8 == 0) {
        float* dstp = agg2 + (size_t)node * HIDDEN + (q8 << 3);
        *(float4*)dstp = make_float4(r[0], r[1], r[2], r[3]);
        *(float4*)(dstp + 4) = make_float4(r[4], r[5], r[6], r[7]);
    }

    // attention score: v = sum_c r[c]*att_w[q8*8+c], reduce across q8
    float v = 0.f;
    #pragma unroll
    for (int c = 0; c < 8; ++c) v = fmaf(r[c], att_w[(q8 << 3) + c], v);
    v += __shfl_xor(v, 1, 64); v += __shfl_xor(v, 2, 64); v += __shfl_xor(v, 4, 64);
    if (lane == 0) {
        float sc = v + att_b[0];
        att_s[node] = (sc > 0.0f) ? sc : LEAKY * sc;
    }
}

// ---------------- graph boundaries (batch sorted) ----------------
__global__ void k_gbounds(const int* __restrict__ batch, int* gs, int* ge) {
    int n = blockIdx.x * 256 + threadIdx.x;
    if (n < N_NODES) {
        int b = batch[n];
        if (n == 0 || batch[n - 1] != b) gs[b] = n;
        if (n == N_NODES - 1 || batch[n + 1] != b) ge[b] = n + 1;
    }
}

// ---------------- fused pool + head MLPs: one block per graph ----------------
__global__ __launch_bounds__(256) void k_pool_head(const float* __restrict__ agg2,
                                                   const float* __restrict__ att_s,
                                                   const int* __restrict__ gs,
                                                   const int* __restrict__ ge,
                                                   const float* __restrict__ proj_w,
                                                   const float* __restrict__ proj_b,
                                                   const float* __restrict__ cls_w1,
                                                   const float* __restrict__ cls_b1,
                                                   const float* __restrict__ cls_w2,
                                                   const float* __restrict__ cls_b2,
                                                   float* __restrict__ out) {
    __shared__ float red[4];
    __shared__ float red2[4 * 64];
    __shared__ float sG[HIDDEN];
    __shared__ float sT1[EMBED];
    __shared__ float sT2[128];
    int gid = blockIdx.x;
    int tid = threadIdx.x, f = tid & 63, w = tid >> 6;
    int s = gs[gid], e = ge[gid];

    // segment max
    float m = -INFINITY;
    for (int n = s + tid; n < e; n += 256) m = fmaxf(m, att_s[n]);
    #pragma unroll
    for (int o = 32; o > 0; o >>= 1) m = fmaxf(m, __shfl_xor(m, o, 64));
    if (f == 0) red[w] = m;
    __syncthreads();
    m = fmaxf(fmaxf(red[0], red[1]), fmaxf(red[2], red[3]));
    __syncthreads();

    // denom
    float z = 0.0f;
    for (int n = s + tid; n < e; n += 256) z += expf(att_s[n] - m);
    #pragma unroll
    for (int o = 32; o > 0; o >>= 1) z += __shfl_xor(z, o, 64);
    if (f == 0) red[w] = z;
    __syncthreads();
    z = red[0] + red[1] + red[2] + red[3];
    float inv = (e > s) ? 1.0f / z : 0.0f;

    // weighted sum
    float acc = 0.0f;
    for (int n = s + w; n < e; n += 4)
        acc = fmaf(expf(att_s[n] - m) * inv, agg2[(size_t)n * HIDDEN + f], acc);
    red2[w * 64 + f] = acc;
    __syncthreads();
    if (w == 0) sG[f] = red2[f] + red2[64 + f] + red2[128 + f] + red2[192 + f];
    __syncthreads();

    // t1 = g @ proj_w + proj_b
    for (int c = tid; c < EMBED; c += 256) {
        float a = proj_b[c];
        #pragma unroll 8
        for (int k = 0; k < HIDDEN; ++k) a = fmaf(sG[k], proj_w[k * EMBED + c], a);
        sT1[c] = a;
    }
    __syncthreads();

    // t2 = relu(t1 @ cls_w1 + cls_b1)
    if (tid < 128) {
        float a = cls_b1[tid];
        for (int k = 0; k < EMBED; ++k) a = fmaf(sT1[k], cls_w1[k * 128 + tid], a);
        sT2[tid] = fmaxf(a, 0.f);
    }
    __syncthreads();

    // out = t2 @ cls_w2 + cls_b2
    if (tid < N_CLASSES) {
        float a = cls_b2[tid];
        #pragma unroll 8
        for (int k = 0; k < 128; ++k) a = fmaf(sT2[k], cls_w2[k * N_CLASSES + tid], a);
        out[gid * N_CLASSES + tid] = a;
    }
}

extern "C" void kernel_launch(void* const* d_in, const int* in_sizes, int n_in,
                              void* d_out, int out_size, void* d_ws, size_t ws_size,
                              hipStream_t stream) {
    const float* x      = (const float*)d_in[0];
    const int*   ei     = (const int*)d_in[1];
    const int*   batch  = (const int*)d_in[2];
    const float* W1     = (const float*)d_in[3];
    const float* b1     = (const float*)d_in[4];
    const float* W2     = (const float*)d_in[5];
    const float* b2     = (const float*)d_in[6];
    const float* att_w  = (const float*)d_in[7];
    const float* att_b  = (const float*)d_in[8];
    const float* proj_w = (const float*)d_in[9];
    const float* proj_b = (const float*)d_in[10];
    const float* cls_w1 = (const float*)d_in[11];
    const float* cls_b1 = (const float*)d_in[12];
    const float* cls_w2 = (const float*)d_in[13];
    const float* cls_b2 = (const float*)d_in[14];
    float* out = (float*)d_out;

    const int* e_src = ei;
    const int* e_dst = ei + N_EDGES;

    // workspace layout (float words; h1/h2 are fp16 so 50000*64 halves = 1.6M words each)
    float* base = (float*)d_ws;
    size_t o = 0;
    float*    dis       = base + o;              o += 50048;
    int*      deg_i     = (int*)(base + o);      o += 50048;
    int*      row_start = (int*)(base + o);      o += 50056;
    int*      partials  = (int*)(base + o);      o += 256;
    unsigned* pk        = (unsigned*)(base + o); o += 800000;
    __half*   h1        = (__half*)(base + o);   o += 1600000;   // 50000*64 fp16 = 6.4 MB
    __half*   h2        = (__half*)(base + o);   o += 1600000;
    float*    agg2      = base + o;              o += 3200000;
    int*      rank      = (int*)agg2;            // alias: rank dead before agg2 written
    float*    att_s     = base + o;              o += 50048;
    int*      gs        = (int*)(base + o);      o += 512;
    int*      ge        = (int*)(base + o);      o += 512;

    const int NB_N    = (N_NODES + 255) / 256;               // 196
    const int NB_E    = (N_EDGES + 255) / 256;               // 3125
    const int NB_GG   = N_NODES / 16;                        // 3125 (exact)
    const int NB_ROW4 = N_NODES / 4;                         // 12500 (exact)
    const int NB_G32  = (N_NODES + G1_ROWS - 1) / G1_ROWS;   // 1563

    // CSR build
    k_zero<<<NB_N, 256, 0, stream>>>(deg_i, gs, ge);
    k_deg_rank<<<NB_E, 256, 0, stream>>>(e_dst, deg_i, rank);
    k_scan1<<<SCAN_BLOCKS, 256, 0, stream>>>(deg_i, row_start, partials, dis);
    k_scan2<<<1, 256, 0, stream>>>(partials);
    k_scan3<<<SCAN_BLOCKS, 256, 0, stream>>>(row_start, partials);
    k_fill<<<NB_E, 256, 0, stream>>>(e_src, e_dst, rank, row_start, dis, pk);

    // conv1 + conv2-transform
    k_gemm1<<<NB_G32, 256, 0, stream>>>(x, W1, h1);
    k_gg<<<NB_GG, 256, 0, stream>>>(h1, pk, row_start, dis, b1, W2, h2);

    // conv2-aggregate + attention score
    k_gather2<<<NB_ROW4, 256, 0, stream>>>(h2, pk, row_start, dis, b2, att_w, att_b,
                                           agg2, att_s);

    // pooling + head (fused)
    k_gbounds<<<NB_N, 256, 0, stream>>>(batch, gs, ge);
    k_pool_head<<<N_GRAPHS, 256, 0, stream>>>(agg2, att_s, gs, ge,
                                              proj_w, proj_b, cls_w1, cls_b1,
                                              cls_w2, cls_b2, out);
}

// Round 9
// 177.130 us; speedup vs baseline: 1.1134x; 1.1134x over previous
//
#include <hip/hip_runtime.h>
#include <hip/hip_fp16.h>
#include <math.h>

#define N_NODES   50000
#define N_EDGES   800000
#define N_FEAT    128
#define HIDDEN    64
#define EMBED     300
#define N_CLASSES 10
#define N_GRAPHS  500
#define LEAKY     0.01f
#define SCAN_BLOCKS ((N_NODES + 255) / 256)  // 196

typedef __attribute__((ext_vector_type(4))) _Float16 half4f;
typedef __attribute__((ext_vector_type(8))) _Float16 half8;
typedef __attribute__((ext_vector_type(4))) float f32x4;

// packed edge: low 16 bits = src node id (50000 < 65536), high 16 = fp16 norm
__device__ __forceinline__ float pk_w(unsigned p) {
    return __half2float(__ushort_as_half((unsigned short)(p >> 16)));
}

// ---------------- init ----------------
__global__ void k_zero(int* deg, int* gs, int* ge) {
    int i = blockIdx.x * 256 + threadIdx.x;
    if (i < N_NODES) deg[i] = 0;
    if (i < N_GRAPHS) { gs[i] = 0; ge[i] = 0; }
}

// ---------------- W1^T fp16 precompute: W1T[n][k] = W1[k][n] ----------------
__global__ void k_w1t(const float* __restrict__ W1, __half* __restrict__ W1T) {
    int idx = blockIdx.x * 256 + threadIdx.x;
    if (idx < N_FEAT * HIDDEN) {
        int n = idx >> 7, k = idx & 127;
        W1T[idx] = __float2half(W1[k * HIDDEN + n]);   // write coalesced
    }
}

// ---------------- degree count + per-edge rank (coalesced rank write) ----------------
__global__ void k_deg_rank(const int* __restrict__ dst, int* deg, int* rank) {
    int e = blockIdx.x * 256 + threadIdx.x;
    if (e < N_EDGES) rank[e] = atomicAdd(&deg[dst[e]], 1);
}

// ---------------- scan: deg -> row_start (exclusive); dis = rsqrt(deg+1) ----------------
__global__ __launch_bounds__(256) void k_scan1(const int* __restrict__ deg, int* row_start,
                                               int* partials, float* dis) {
    __shared__ int wsum[4];
    int i = blockIdx.x * 256 + threadIdx.x;
    int v = (i < N_NODES) ? deg[i] : 0;
    int lane = threadIdx.x & 63, wid = threadIdx.x >> 6;
    int s = v;
    #pragma unroll
    for (int off = 1; off < 64; off <<= 1) {
        int t = __shfl_up(s, off, 64);
        if (lane >= off) s += t;
    }
    if (lane == 63) wsum[wid] = s;
    __syncthreads();
    int woff = 0;
    for (int w = 0; w < wid; ++w) woff += wsum[w];
    if (i < N_NODES) {
        row_start[i] = woff + s - v;
        dis[i] = rsqrtf((float)(deg[i] + 1));
    }
    if (threadIdx.x == 255) partials[blockIdx.x] = woff + s;
}

__global__ __launch_bounds__(256) void k_scan2(int* partials) {
    __shared__ int wsum[4];
    int v = (threadIdx.x < SCAN_BLOCKS) ? partials[threadIdx.x] : 0;
    int lane = threadIdx.x & 63, wid = threadIdx.x >> 6;
    int s = v;
    #pragma unroll
    for (int off = 1; off < 64; off <<= 1) {
        int t = __shfl_up(s, off, 64);
        if (lane >= off) s += t;
    }
    if (lane == 63) wsum[wid] = s;
    __syncthreads();
    int woff = 0;
    for (int w = 0; w < wid; ++w) woff += wsum[w];
    if (threadIdx.x < SCAN_BLOCKS) partials[threadIdx.x] = woff + s - v;
}

__global__ void k_scan3(int* row_start, const int* __restrict__ partials) {
    int i = blockIdx.x * 256 + threadIdx.x;
    if (i < N_NODES) row_start[i] += partials[blockIdx.x];
    if (i == 0) row_start[N_NODES] = N_EDGES;
}

// ---------------- CSR fill: one packed 4B scatter per edge ----------------
__global__ void k_fill(const int* __restrict__ src, const int* __restrict__ dst,
                       const int* __restrict__ rank, const int* __restrict__ row_start,
                       const float* __restrict__ dis, unsigned* __restrict__ pk) {
    int e = blockIdx.x * 256 + threadIdx.x;
    if (e < N_EDGES) {
        int s = src[e], d = dst[e];
        float w = dis[s] * dis[d];
        unsigned short wh = __half_as_ushort(__float2half(w));
        pk[row_start[d] + rank[e]] = (unsigned)s | ((unsigned)wh << 16);
    }
}

// ---------------- GEMM1 (MFMA): h1 = x @ W1, fp16 out ----------------
// 64 rows/block, 4 waves, wave = 16 rows x 64 cols; K=128 in 4 steps of 32.
// A: row=lane&15, k=(lane>>4)*8+reg (from x, cvt to fp16).
// B: col=lane&15, k=(lane>>4)*8+reg (16B contiguous from W1T[n][k]).
// D: col=lane&15, row=(lane>>4)*4+reg.
__global__ __launch_bounds__(256) void k_gemm1(const float* __restrict__ x,
                                               const __half* __restrict__ W1T,
                                               __half* __restrict__ h) {
    int tid = threadIdx.x, wid = tid >> 6, lane = tid & 63;
    int r16 = lane & 15, kg = lane >> 4;
    int rowbase = blockIdx.x * 64 + wid * 16;
    int arow = rowbase + r16;
    bool avalid = arow < N_NODES;
    const float* xr = x + (size_t)arow * N_FEAT;

    half8 a[4];
    #pragma unroll
    for (int kt = 0; kt < 4; ++kt) {
        int k0 = kt * 32 + kg * 8;
        float4 u = avalid ? *(const float4*)(xr + k0)     : make_float4(0.f, 0.f, 0.f, 0.f);
        float4 v = avalid ? *(const float4*)(xr + k0 + 4) : make_float4(0.f, 0.f, 0.f, 0.f);
        a[kt][0] = (_Float16)u.x; a[kt][1] = (_Float16)u.y;
        a[kt][2] = (_Float16)u.z; a[kt][3] = (_Float16)u.w;
        a[kt][4] = (_Float16)v.x; a[kt][5] = (_Float16)v.y;
        a[kt][6] = (_Float16)v.z; a[kt][7] = (_Float16)v.w;
    }

    #pragma unroll
    for (int nt = 0; nt < 4; ++nt) {
        f32x4 acc = {0.f, 0.f, 0.f, 0.f};
        const _Float16* wp = (const _Float16*)W1T + (size_t)(nt * 16 + r16) * N_FEAT + kg * 8;
        #pragma unroll
        for (int kt = 0; kt < 4; ++kt) {
            half8 b = *(const half8*)(wp + kt * 32);
            acc = __builtin_amdgcn_mfma_f32_16x16x32_f16(a[kt], b, acc, 0, 0, 0);
        }
        int col = nt * 16 + r16;
        #pragma unroll
        for (int r = 0; r < 4; ++r) {
            int row = rowbase + kg * 4 + r;
            if (row < N_NODES) h[(size_t)row * HIDDEN + col] = __float2half(acc[r]);
        }
    }
}

// ---------------- gather core (R7): coalesced pk preload + shfl broadcast ----------------
// lane = [g4 = edge slot (lane>>4)][q = feature quad (lane&15)], 8B h loads.
__device__ __forceinline__ void gather4pk(const __half* __restrict__ h,
                                          const unsigned* __restrict__ pk,
                                          int s, int e, int lane, int g4, int q,
                                          float4& acc) {
    for (int cs = s; cs < e; cs += 64) {
        unsigned pkv = (cs + lane < e) ? pk[cs + lane] : 0u;
        int avail = e - cs; if (avail > 64) avail = 64;
        int iters = (avail + 3) >> 2;
        #pragma unroll 2
        for (int t = 0; t < iters; ++t) {
            unsigned p = __shfl(pkv, t * 4 + g4, 64);   // w=0 for padded slots
            float w = pk_w(p);
            half4f hv = *(const half4f*)(h + ((size_t)(p & 0xFFFFu)) * HIDDEN + (q << 2));
            acc.x = fmaf(w, (float)hv.x, acc.x);
            acc.y = fmaf(w, (float)hv.y, acc.y);
            acc.z = fmaf(w, (float)hv.z, acc.z);
            acc.w = fmaf(w, (float)hv.w, acc.w);
        }
    }
}

__device__ __forceinline__ void xreduce(float4& a) {
    a.x += __shfl_xor(a.x, 16, 64); a.y += __shfl_xor(a.y, 16, 64);
    a.z += __shfl_xor(a.z, 16, 64); a.w += __shfl_xor(a.w, 16, 64);
    a.x += __shfl_xor(a.x, 32, 64); a.y += __shfl_xor(a.y, 32, 64);
    a.z += __shfl_xor(a.z, 32, 64); a.w += __shfl_xor(a.w, 32, 64);
}

// ---------------- fused conv1-gather + gemm2, 16 nodes/block ----------------
__global__ __launch_bounds__(256) void k_gg(const __half* __restrict__ h1,
                                            const unsigned* __restrict__ pk,
                                            const int* __restrict__ row_start,
                                            const float* __restrict__ dis,
                                            const float* __restrict__ b1,
                                            const float* __restrict__ W2,
                                            __half* __restrict__ h2) {
    __shared__ float sW[HIDDEN * HIDDEN];  // 16 KB
    __shared__ float sa[16 * HIDDEN];      // 4 KB
    {
        const float4* W4 = (const float4*)W2;
        float4* sW4 = (float4*)sW;
        #pragma unroll
        for (int i = 0; i < 4; ++i)
            sW4[i * 256 + threadIdx.x] = W4[i * 256 + threadIdx.x];
    }

    int tid = threadIdx.x, wid = tid >> 6, lane = tid & 63;
    int g4 = lane >> 4, q = lane & 15;
    int base = blockIdx.x * 16 + wid * 4;   // grid exact: 50000 = 3125*16
    #pragma unroll
    for (int i = 0; i < 4; ++i) {
        int node = base + i;
        int s = row_start[node], e = row_start[node + 1];
        float4 acc = {0.f, 0.f, 0.f, 0.f};
        gather4pk(h1, pk, s, e, lane, g4, q, acc);
        xreduce(acc);
        float dv = dis[node], dd = dv * dv;
        half4f sv = *(const half4f*)(h1 + (size_t)node * HIDDEN + (q << 2));
        float4 bv = *(const float4*)(b1 + (q << 2));
        float4 r;
        r.x = fmaxf(fmaf((float)sv.x, dd, bv.x) + acc.x, 0.f);
        r.y = fmaxf(fmaf((float)sv.y, dd, bv.y) + acc.y, 0.f);
        r.z = fmaxf(fmaf((float)sv.z, dd, bv.z) + acc.z, 0.f);
        r.w = fmaxf(fmaf((float)sv.w, dd, bv.w) + acc.w, 0.f);
        if (g4 == 0) *(float4*)&sa[(wid * 4 + i) * HIDDEN + (q << 2)] = r;
    }
    __syncthreads();

    // joint 4-node matvec: one sW read feeds 4 FMAs
    int f = lane;
    float o0 = 0.f, o1 = 0.f, o2 = 0.f, o3 = 0.f;
    const float* sa0 = &sa[wid * 4 * HIDDEN];
    #pragma unroll 8
    for (int k = 0; k < HIDDEN; ++k) {
        float wv = sW[k * HIDDEN + f];
        o0 = fmaf(sa0[k], wv, o0);
        o1 = fmaf(sa0[HIDDEN + k], wv, o1);
        o2 = fmaf(sa0[2 * HIDDEN + k], wv, o2);
        o3 = fmaf(sa0[3 * HIDDEN + k], wv, o3);
    }
    h2[(size_t)(base + 0) * HIDDEN + f] = __float2half(o0);
    h2[(size_t)(base + 1) * HIDDEN + f] = __float2half(o1);
    h2[(size_t)(base + 2) * HIDDEN + f] = __float2half(o2);
    h2[(size_t)(base + 3) * HIDDEN + f] = __float2half(o3);
}

// ---------------- conv2-gather + fused attention score, 1 node/wave ----------------
__global__ __launch_bounds__(256) void k_gather2(const __half* __restrict__ h2,
                                                 const unsigned* __restrict__ pk,
                                                 const int* __restrict__ row_start,
                                                 const float* __restrict__ dis,
                                                 const float* __restrict__ b2,
                                                 const float* __restrict__ att_w,
                                                 const float* __restrict__ att_b,
                                                 float* __restrict__ agg2,
                                                 float* __restrict__ att_s) {
    int tid = threadIdx.x, wid = tid >> 6, lane = tid & 63;
    int g4 = lane >> 4, q = lane & 15;
    int node = blockIdx.x * 4 + wid;   // grid exact: 12500*4 = 50000
    int s = row_start[node], e = row_start[node + 1];
    float4 acc = {0.f, 0.f, 0.f, 0.f};
    gather4pk(h2, pk, s, e, lane, g4, q, acc);
    xreduce(acc);
    float dv = dis[node], dd = dv * dv;
    half4f sv = *(const half4f*)(h2 + (size_t)node * HIDDEN + (q << 2));
    float4 bv = *(const float4*)(b2 + (q << 2));
    float4 r;
    r.x = fmaxf(fmaf((float)sv.x, dd, bv.x) + acc.x, 0.f);
    r.y = fmaxf(fmaf((float)sv.y, dd, bv.y) + acc.y, 0.f);
    r.z = fmaxf(fmaf((float)sv.z, dd, bv.z) + acc.z, 0.f);
    r.w = fmaxf(fmaf((float)sv.w, dd, bv.w) + acc.w, 0.f);
    if (g4 == 0) *(float4*)(agg2 + (size_t)node * HIDDEN + (q << 2)) = r;

    float4 aw = *(const float4*)(att_w + (q << 2));
    float v = fmaf(r.x, aw.x, fmaf(r.y, aw.y, fmaf(r.z, aw.z, r.w * aw.w)));
    v += __shfl_xor(v, 1, 64); v += __shfl_xor(v, 2, 64);
    v += __shfl_xor(v, 4, 64); v += __shfl_xor(v, 8, 64);
    if (lane == 0) {
        float sc = v + att_b[0];
        att_s[node] = (sc > 0.0f) ? sc : LEAKY * sc;
    }
}

// ---------------- graph boundaries (batch sorted) ----------------
__global__ void k_gbounds(const int* __restrict__ batch, int* gs, int* ge) {
    int n = blockIdx.x * 256 + threadIdx.x;
    if (n < N_NODES) {
        int b = batch[n];
        if (n == 0 || batch[n - 1] != b) gs[b] = n;
        if (n == N_NODES - 1 || batch[n + 1] != b) ge[b] = n + 1;
    }
}

// ---------------- fused pool + head MLPs: one block per graph ----------------
__global__ __launch_bounds__(256) void k_pool_head(const float* __restrict__ agg2,
                                                   const float* __restrict__ att_s,
                                                   const int* __restrict__ gs,
                                                   const int* __restrict__ ge,
                                                   const float* __restrict__ proj_w,
                                                   const float* __restrict__ proj_b,
                                                   const float* __restrict__ cls_w1,
                                                   const float* __restrict__ cls_b1,
                                                   const float* __restrict__ cls_w2,
                                                   const float* __restrict__ cls_b2,
                                                   float* __restrict__ out) {
    __shared__ float red[4];
    __shared__ float red2[4 * 64];
    __shared__ float sG[HIDDEN];
    __shared__ float sT1[EMBED];
    __shared__ float sT2[128];
    int gid = blockIdx.x;
    int tid = threadIdx.x, f = tid & 63, w = tid >> 6;
    int s = gs[gid], e = ge[gid];

    // segment max
    float m = -INFINITY;
    for (int n = s + tid; n < e; n += 256) m = fmaxf(m, att_s[n]);
    #pragma unroll
    for (int o = 32; o > 0; o >>= 1) m = fmaxf(m, __shfl_xor(m, o, 64));
    if (f == 0) red[w] = m;
    __syncthreads();
    m = fmaxf(fmaxf(red[0], red[1]), fmaxf(red[2], red[3]));
    __syncthreads();

    // denom
    float z = 0.0f;
    for (int n = s + tid; n < e; n += 256) z += expf(att_s[n] - m);
    #pragma unroll
    for (int o = 32; o > 0; o >>= 1) z += __shfl_xor(z, o, 64);
    if (f == 0) red[w] = z;
    __syncthreads();
    z = red[0] + red[1] + red[2] + red[3];
    float inv = (e > s) ? 1.0f / z : 0.0f;

    // weighted sum
    float acc = 0.0f;
    for (int n = s + w; n < e; n += 4)
        acc = fmaf(expf(att_s[n] - m) * inv, agg2[(size_t)n * HIDDEN + f], acc);
    red2[w * 64 + f] = acc;
    __syncthreads();
    if (w == 0) sG[f] = red2[f] + red2[64 + f] + red2[128 + f] + red2[192 + f];
    __syncthreads();

    // t1 = g @ proj_w + proj_b
    for (int c = tid; c < EMBED; c += 256) {
        float a = proj_b[c];
        #pragma unroll 8
        for (int k = 0; k < HIDDEN; ++k) a = fmaf(sG[k], proj_w[k * EMBED + c], a);
        sT1[c] = a;
    }
    __syncthreads();

    // t2 = relu(t1 @ cls_w1 + cls_b1)
    if (tid < 128) {
        float a = cls_b1[tid];
        for (int k = 0; k < EMBED; ++k) a = fmaf(sT1[k], cls_w1[k * 128 + tid], a);
        sT2[tid] = fmaxf(a, 0.f);
    }
    __syncthreads();

    // out = t2 @ cls_w2 + cls_b2
    if (tid < N_CLASSES) {
        float a = cls_b2[tid];
        #pragma unroll 8
        for (int k = 0; k < 128; ++k) a = fmaf(sT2[k], cls_w2[k * N_CLASSES + tid], a);
        out[gid * N_CLASSES + tid] = a;
    }
}

extern "C" void kernel_launch(void* const* d_in, const int* in_sizes, int n_in,
                              void* d_out, int out_size, void* d_ws, size_t ws_size,
                              hipStream_t stream) {
    const float* x      = (const float*)d_in[0];
    const int*   ei     = (const int*)d_in[1];
    const int*   batch  = (const int*)d_in[2];
    const float* W1     = (const float*)d_in[3];
    const float* b1     = (const float*)d_in[4];
    const float* W2     = (const float*)d_in[5];
    const float* b2     = (const float*)d_in[6];
    const float* att_w  = (const float*)d_in[7];
    const float* att_b  = (const float*)d_in[8];
    const float* proj_w = (const float*)d_in[9];
    const float* proj_b = (const float*)d_in[10];
    const float* cls_w1 = (const float*)d_in[11];
    const float* cls_b1 = (const float*)d_in[12];
    const float* cls_w2 = (const float*)d_in[13];
    const float* cls_b2 = (const float*)d_in[14];
    float* out = (float*)d_out;

    const int* e_src = ei;
    const int* e_dst = ei + N_EDGES;

    // workspace layout (float words; every buffer 128B-aligned: sizes multiple of 32 words)
    float* base = (float*)d_ws;
    size_t o = 0;
    float*    dis       = base + o;              o += 50048;
    int*      deg_i     = (int*)(base + o);      o += 50048;
    int*      row_start = (int*)(base + o);      o += 50080;   // N+1 used, padded
    int*      partials  = (int*)(base + o);      o += 256;
    unsigned* pk        = (unsigned*)(base + o); o += 800000;
    __half*   h1        = (__half*)(base + o);   o += 1600000; // 50000*64 fp16, 128B-aligned rows
    __half*   h2        = (__half*)(base + o);   o += 1600000;
    float*    agg2      = base + o;              o += 3200000;
    int*      rank      = (int*)agg2;            // alias: rank dead before agg2 written
    float*    att_s     = base + o;              o += 50048;
    int*      gs        = (int*)(base + o);      o += 512;
    int*      ge        = (int*)(base + o);      o += 512;
    __half*   W1T       = (__half*)(base + o);   o += 4096;    // 64x128 fp16

    const int NB_N    = (N_NODES + 255) / 256;               // 196
    const int NB_E    = (N_EDGES + 255) / 256;               // 3125
    const int NB_GG   = N_NODES / 16;                        // 3125 (exact)
    const int NB_ROW4 = N_NODES / 4;                         // 12500 (exact)
    const int NB_M64  = (N_NODES + 63) / 64;                 // 782

    // CSR build
    k_zero<<<NB_N, 256, 0, stream>>>(deg_i, gs, ge);
    k_w1t<<<(N_FEAT * HIDDEN + 255) / 256, 256, 0, stream>>>(W1, W1T);
    k_deg_rank<<<NB_E, 256, 0, stream>>>(e_dst, deg_i, rank);
    k_scan1<<<SCAN_BLOCKS, 256, 0, stream>>>(deg_i, row_start, partials, dis);
    k_scan2<<<1, 256, 0, stream>>>(partials);
    k_scan3<<<SCAN_BLOCKS, 256, 0, stream>>>(row_start, partials);
    k_fill<<<NB_E, 256, 0, stream>>>(e_src, e_dst, rank, row_start, dis, pk);

    // conv1 (MFMA) + conv2-transform
    k_gemm1<<<NB_M64, 256, 0, stream>>>(x, W1T, h1);
    k_gg<<<NB_GG, 256, 0, stream>>>(h1, pk, row_start, dis, b1, W2, h2);

    // conv2-aggregate + attention score
    k_gather2<<<NB_ROW4, 256, 0, stream>>>(h2, pk, row_start, dis, b2, att_w, att_b,
                                           agg2, att_s);

    // pooling + head (fused)
    k_gbounds<<<NB_N, 256, 0, stream>>>(batch, gs, ge);
    k_pool_head<<<N_GRAPHS, 256, 0, stream>>>(agg2, att_s, gs, ge,
                                              proj_w, proj_b, cls_w1, cls_b1,
                                              cls_w2, cls_b2, out);
}

// Round 10
// 163.757 us; speedup vs baseline: 1.2043x; 1.0817x over previous
//
#include <hip/hip_runtime.h>
#include <hip/hip_fp16.h>
#include <math.h>

#define N_NODES   50000
#define N_EDGES   800000
#define N_FEAT    128
#define HIDDEN    64
#define EMBED     300
#define N_CLASSES 10
#define N_GRAPHS  500
#define LEAKY     0.01f
#define SCAN_BLOCKS 196
#define NB_FILL   3125
#define NB_G2     12500

typedef __attribute__((ext_vector_type(4))) _Float16 half4f;
typedef __attribute__((ext_vector_type(8))) _Float16 half8;
typedef __attribute__((ext_vector_type(4))) float f32x4;

// packed edge: low 16 bits = src node id (50000 < 65536), high 16 = fp16 norm
__device__ __forceinline__ float pk_w(unsigned p) {
    return __half2float(__ushort_as_half((unsigned short)(p >> 16)));
}

// ---------------- kA: zero(deg,gs,ge) + W1T + W2T precompute (independent work) ----------------
__global__ void kA(int* deg, int* gs, int* ge,
                   const float* __restrict__ W1, __half* __restrict__ W1T,
                   const float* __restrict__ W2, __half* __restrict__ W2T) {
    int bid = blockIdx.x, tid = threadIdx.x;
    if (bid < 196) {
        int i = bid * 256 + tid;
        if (i < N_NODES) deg[i] = 0;
        if (i < N_GRAPHS) { gs[i] = 0; ge[i] = 0; }
    } else if (bid < 228) {
        int idx = (bid - 196) * 256 + tid;            // 8192 = 128*64
        int n = idx >> 7, k = idx & 127;
        W1T[idx] = __float2half(W1[k * HIDDEN + n]);  // W1T[n][k]
    } else {
        int idx = (bid - 228) * 256 + tid;            // 4096 = 64*64
        int n = idx >> 6, k = idx & 63;
        W2T[idx] = __float2half(W2[k * HIDDEN + n]);  // W2T[n][k]
    }
}

// ---------------- degree count + per-edge rank (coalesced rank write) ----------------
__global__ void k_deg_rank(const int* __restrict__ dst, int* deg, int* rank) {
    int e = blockIdx.x * 256 + threadIdx.x;
    if (e < N_EDGES) rank[e] = atomicAdd(&deg[dst[e]], 1);
}

// ---------------- scan1: block-local exclusive scan; dis = rsqrt(deg+1) ----------------
__global__ __launch_bounds__(256) void k_scan1(const int* __restrict__ deg, int* row_start,
                                               int* partials, float* dis) {
    __shared__ int wsum[4];
    int i = blockIdx.x * 256 + threadIdx.x;
    int v = (i < N_NODES) ? deg[i] : 0;
    int lane = threadIdx.x & 63, wid = threadIdx.x >> 6;
    int s = v;
    #pragma unroll
    for (int off = 1; off < 64; off <<= 1) {
        int t = __shfl_up(s, off, 64);
        if (lane >= off) s += t;
    }
    if (lane == 63) wsum[wid] = s;
    __syncthreads();
    int woff = 0;
    for (int w = 0; w < wid; ++w) woff += wsum[w];
    if (i < N_NODES) {
        row_start[i] = woff + s - v;
        dis[i] = rsqrtf((float)(deg[i] + 1));
    }
    if (threadIdx.x == 255) partials[blockIdx.x] = woff + s;
}

// ---------------- scan3b: add prefix (masked sum of partials) — merges old scan2+scan3 ----------------
__global__ __launch_bounds__(256) void k_scan3b(int* row_start, const int* __restrict__ partials) {
    __shared__ int wsum[4];
    int bid = blockIdx.x, tid = threadIdx.x;
    int lane = tid & 63, wid = tid >> 6;
    int v = (tid < SCAN_BLOCKS && tid < bid) ? partials[tid] : 0;
    #pragma unroll
    for (int off = 32; off > 0; off >>= 1) v += __shfl_xor(v, off, 64);
    if (lane == 0) wsum[wid] = v;
    __syncthreads();
    int prefix = wsum[0] + wsum[1] + wsum[2] + wsum[3];
    int i = bid * 256 + tid;
    if (i < N_NODES) row_start[i] += prefix;
    if (i == 0) row_start[N_NODES] = N_EDGES;
}

// ---------------- kB: CSR fill (blocks 0..3124) || MFMA gemm1 (blocks 3125..3906) ----------------
__global__ __launch_bounds__(256) void kB(const int* __restrict__ src, const int* __restrict__ dst,
                                          const int* __restrict__ rank, const int* __restrict__ row_start,
                                          const float* __restrict__ dis, unsigned* __restrict__ pk,
                                          const float* __restrict__ x, const __half* __restrict__ W1T,
                                          __half* __restrict__ h1) {
    if (blockIdx.x < NB_FILL) {
        int e = blockIdx.x * 256 + threadIdx.x;
        if (e < N_EDGES) {
            int s = src[e], d = dst[e];
            float w = dis[s] * dis[d];
            unsigned short wh = __half_as_ushort(__float2half(w));
            pk[row_start[d] + rank[e]] = (unsigned)s | ((unsigned)wh << 16);
        }
        return;
    }
    // gemm1: h1 = x @ W1 (MFMA 16x16x32_f16), 64 rows/block
    int tid = threadIdx.x, wid = tid >> 6, lane = tid & 63;
    int r16 = lane & 15, kg = lane >> 4;
    int rowbase = (blockIdx.x - NB_FILL) * 64 + wid * 16;
    int arow = rowbase + r16;
    bool avalid = arow < N_NODES;
    const float* xr = x + (size_t)arow * N_FEAT;

    half8 a[4];
    #pragma unroll
    for (int kt = 0; kt < 4; ++kt) {
        int k0 = kt * 32 + kg * 8;
        float4 u = avalid ? *(const float4*)(xr + k0)     : make_float4(0.f, 0.f, 0.f, 0.f);
        float4 v = avalid ? *(const float4*)(xr + k0 + 4) : make_float4(0.f, 0.f, 0.f, 0.f);
        a[kt][0] = (_Float16)u.x; a[kt][1] = (_Float16)u.y;
        a[kt][2] = (_Float16)u.z; a[kt][3] = (_Float16)u.w;
        a[kt][4] = (_Float16)v.x; a[kt][5] = (_Float16)v.y;
        a[kt][6] = (_Float16)v.z; a[kt][7] = (_Float16)v.w;
    }
    #pragma unroll
    for (int nt = 0; nt < 4; ++nt) {
        f32x4 acc = {0.f, 0.f, 0.f, 0.f};
        const _Float16* wp = (const _Float16*)W1T + (size_t)(nt * 16 + r16) * N_FEAT + kg * 8;
        #pragma unroll
        for (int kt = 0; kt < 4; ++kt) {
            half8 b = *(const half8*)(wp + kt * 32);
            acc = __builtin_amdgcn_mfma_f32_16x16x32_f16(a[kt], b, acc, 0, 0, 0);
        }
        int col = nt * 16 + r16;
        #pragma unroll
        for (int r = 0; r < 4; ++r) {
            int row = rowbase + kg * 4 + r;
            if (row < N_NODES) h1[(size_t)row * HIDDEN + col] = __float2half(acc[r]);
        }
    }
}

// ---------------- gather core (R7 form): coalesced pk preload + shfl broadcast ----------------
__device__ __forceinline__ void gather4pk(const __half* __restrict__ h,
                                          const unsigned* __restrict__ pk,
                                          int s, int e, int lane, int g4, int q,
                                          float4& acc) {
    for (int cs = s; cs < e; cs += 64) {
        unsigned pkv = (cs + lane < e) ? pk[cs + lane] : 0u;
        int avail = e - cs; if (avail > 64) avail = 64;
        int iters = (avail + 3) >> 2;
        #pragma unroll 2
        for (int t = 0; t < iters; ++t) {
            unsigned p = __shfl(pkv, t * 4 + g4, 64);   // w=0 for padded slots
            float w = pk_w(p);
            half4f hv = *(const half4f*)(h + ((size_t)(p & 0xFFFFu)) * HIDDEN + (q << 2));
            acc.x = fmaf(w, (float)hv.x, acc.x);
            acc.y = fmaf(w, (float)hv.y, acc.y);
            acc.z = fmaf(w, (float)hv.z, acc.z);
            acc.w = fmaf(w, (float)hv.w, acc.w);
        }
    }
}

__device__ __forceinline__ void xreduce(float4& a) {
    a.x += __shfl_xor(a.x, 16, 64); a.y += __shfl_xor(a.y, 16, 64);
    a.z += __shfl_xor(a.z, 16, 64); a.w += __shfl_xor(a.w, 16, 64);
    a.x += __shfl_xor(a.x, 32, 64); a.y += __shfl_xor(a.y, 32, 64);
    a.z += __shfl_xor(a.z, 32, 64); a.w += __shfl_xor(a.w, 32, 64);
}

// ---------------- k_gg: conv1-gather + MFMA gemm2, 16 nodes/block ----------------
__global__ __launch_bounds__(256) void k_gg(const __half* __restrict__ h1,
                                            const unsigned* __restrict__ pk,
                                            const int* __restrict__ row_start,
                                            const float* __restrict__ dis,
                                            const float* __restrict__ b1,
                                            const __half* __restrict__ W2T,
                                            __half* __restrict__ h2) {
    __shared__ __align__(16) __half sa[16 * 72];   // padded stride 72 halves = 144B (bank-safe)
    int tid = threadIdx.x, wid = tid >> 6, lane = tid & 63;
    int g4 = lane >> 4, q = lane & 15;
    int base = blockIdx.x * 16 + wid * 4;   // grid exact: 50000 = 3125*16
    #pragma unroll
    for (int i = 0; i < 4; ++i) {
        int node = base + i;
        int s = row_start[node], e = row_start[node + 1];
        float4 acc = {0.f, 0.f, 0.f, 0.f};
        gather4pk(h1, pk, s, e, lane, g4, q, acc);
        xreduce(acc);
        float dv = dis[node], dd = dv * dv;
        half4f sv = *(const half4f*)(h1 + (size_t)node * HIDDEN + (q << 2));
        float4 bv = *(const float4*)(b1 + (q << 2));
        if (g4 == 0) {
            half4f r;
            r.x = (_Float16)fmaxf(fmaf((float)sv.x, dd, bv.x) + acc.x, 0.f);
            r.y = (_Float16)fmaxf(fmaf((float)sv.y, dd, bv.y) + acc.y, 0.f);
            r.z = (_Float16)fmaxf(fmaf((float)sv.z, dd, bv.z) + acc.z, 0.f);
            r.w = (_Float16)fmaxf(fmaf((float)sv.w, dd, bv.w) + acc.w, 0.f);
            *(half4f*)&sa[(wid * 4 + i) * 72 + (q << 2)] = r;
        }
    }
    __syncthreads();

    // MFMA: D[16 nodes][64 cols]; wave wid computes col-tile [wid*16, wid*16+16)
    int r16 = lane & 15, kg = lane >> 4;
    f32x4 acc = {0.f, 0.f, 0.f, 0.f};
    const _Float16* wp = (const _Float16*)W2T + (size_t)(wid * 16 + r16) * HIDDEN + kg * 8;
    #pragma unroll
    for (int kt = 0; kt < 2; ++kt) {
        half8 a = *(const half8*)&sa[r16 * 72 + kt * 32 + kg * 8];
        half8 b = *(const half8*)(wp + kt * 32);
        acc = __builtin_amdgcn_mfma_f32_16x16x32_f16(a, b, acc, 0, 0, 0);
    }
    int col = wid * 16 + r16;
    int nodebase = blockIdx.x * 16;
    #pragma unroll
    for (int r = 0; r < 4; ++r) {
        int row = nodebase + kg * 4 + r;
        h2[(size_t)row * HIDDEN + col] = __float2half(acc[r]);
    }
}

// ---------------- kC: conv2-gather + att score (blocks 0..12499) || gbounds (12500..) ----------------
__global__ __launch_bounds__(256) void kC(const __half* __restrict__ h2,
                                          const unsigned* __restrict__ pk,
                                          const int* __restrict__ row_start,
                                          const float* __restrict__ dis,
                                          const float* __restrict__ b2,
                                          const float* __restrict__ att_w,
                                          const float* __restrict__ att_b,
                                          __half* __restrict__ agg2,
                                          float* __restrict__ att_s,
                                          const int* __restrict__ batch,
                                          int* gs, int* ge) {
    if (blockIdx.x >= NB_G2) {
        int n = (blockIdx.x - NB_G2) * 256 + threadIdx.x;
        if (n < N_NODES) {
            int b = batch[n];
            if (n == 0 || batch[n - 1] != b) gs[b] = n;
            if (n == N_NODES - 1 || batch[n + 1] != b) ge[b] = n + 1;
        }
        return;
    }
    int tid = threadIdx.x, wid = tid >> 6, lane = tid & 63;
    int g4 = lane >> 4, q = lane & 15;
    int node = blockIdx.x * 4 + wid;   // grid exact: 12500*4 = 50000
    int s = row_start[node], e = row_start[node + 1];
    float4 acc = {0.f, 0.f, 0.f, 0.f};
    gather4pk(h2, pk, s, e, lane, g4, q, acc);
    xreduce(acc);
    float dv = dis[node], dd = dv * dv;
    half4f sv = *(const half4f*)(h2 + (size_t)node * HIDDEN + (q << 2));
    float4 bv = *(const float4*)(b2 + (q << 2));
    float4 r;
    r.x = fmaxf(fmaf((float)sv.x, dd, bv.x) + acc.x, 0.f);
    r.y = fmaxf(fmaf((float)sv.y, dd, bv.y) + acc.y, 0.f);
    r.z = fmaxf(fmaf((float)sv.z, dd, bv.z) + acc.z, 0.f);
    r.w = fmaxf(fmaf((float)sv.w, dd, bv.w) + acc.w, 0.f);
    if (g4 == 0) {
        half4f rh;
        rh.x = (_Float16)r.x; rh.y = (_Float16)r.y;
        rh.z = (_Float16)r.z; rh.w = (_Float16)r.w;
        *(half4f*)(agg2 + (size_t)node * HIDDEN + (q << 2)) = rh;
    }

    float4 aw = *(const float4*)(att_w + (q << 2));
    float v = fmaf(r.x, aw.x, fmaf(r.y, aw.y, fmaf(r.z, aw.z, r.w * aw.w)));
    v += __shfl_xor(v, 1, 64); v += __shfl_xor(v, 2, 64);
    v += __shfl_xor(v, 4, 64); v += __shfl_xor(v, 8, 64);
    if (lane == 0) {
        float sc = v + att_b[0];
        att_s[node] = (sc > 0.0f) ? sc : LEAKY * sc;
    }
}

// ---------------- fused pool + head MLPs: one block per graph ----------------
__global__ __launch_bounds__(256) void k_pool_head(const __half* __restrict__ agg2,
                                                   const float* __restrict__ att_s,
                                                   const int* __restrict__ gs,
                                                   const int* __restrict__ ge,
                                                   const float* __restrict__ proj_w,
                                                   const float* __restrict__ proj_b,
                                                   const float* __restrict__ cls_w1,
                                                   const float* __restrict__ cls_b1,
                                                   const float* __restrict__ cls_w2,
                                                   const float* __restrict__ cls_b2,
                                                   float* __restrict__ out) {
    __shared__ float red[4];
    __shared__ float red2[4 * 64];
    __shared__ float sG[HIDDEN];
    __shared__ float sT1[EMBED];
    __shared__ float sT2[128];
    int gid = blockIdx.x;
    int tid = threadIdx.x, f = tid & 63, w = tid >> 6;
    int s = gs[gid], e = ge[gid];

    // segment max
    float m = -INFINITY;
    for (int n = s + tid; n < e; n += 256) m = fmaxf(m, att_s[n]);
    #pragma unroll
    for (int o = 32; o > 0; o >>= 1) m = fmaxf(m, __shfl_xor(m, o, 64));
    if (f == 0) red[w] = m;
    __syncthreads();
    m = fmaxf(fmaxf(red[0], red[1]), fmaxf(red[2], red[3]));
    __syncthreads();

    // denom
    float z = 0.0f;
    for (int n = s + tid; n < e; n += 256) z += expf(att_s[n] - m);
    #pragma unroll
    for (int o = 32; o > 0; o >>= 1) z += __shfl_xor(z, o, 64);
    if (f == 0) red[w] = z;
    __syncthreads();
    z = red[0] + red[1] + red[2] + red[3];
    float inv = (e > s) ? 1.0f / z : 0.0f;

    // weighted sum
    float acc = 0.0f;
    for (int n = s + w; n < e; n += 4)
        acc = fmaf(expf(att_s[n] - m) * inv,
                   __half2float(agg2[(size_t)n * HIDDEN + f]), acc);
    red2[w * 64 + f] = acc;
    __syncthreads();
    if (w == 0) sG[f] = red2[f] + red2[64 + f] + red2[128 + f] + red2[192 + f];
    __syncthreads();

    // t1 = g @ proj_w + proj_b
    for (int c = tid; c < EMBED; c += 256) {
        float a = proj_b[c];
        #pragma unroll 8
        for (int k = 0; k < HIDDEN; ++k) a = fmaf(sG[k], proj_w[k * EMBED + c], a);
        sT1[c] = a;
    }
    __syncthreads();

    // t2 = relu(t1 @ cls_w1 + cls_b1)
    if (tid < 128) {
        float a = cls_b1[tid];
        for (int k = 0; k < EMBED; ++k) a = fmaf(sT1[k], cls_w1[k * 128 + tid], a);
        sT2[tid] = fmaxf(a, 0.f);
    }
    __syncthreads();

    // out = t2 @ cls_w2 + cls_b2
    if (tid < N_CLASSES) {
        float a = cls_b2[tid];
        #pragma unroll 8
        for (int k = 0; k < 128; ++k) a = fmaf(sT2[k], cls_w2[k * N_CLASSES + tid], a);
        out[gid * N_CLASSES + tid] = a;
    }
}

extern "C" void kernel_launch(void* const* d_in, const int* in_sizes, int n_in,
                              void* d_out, int out_size, void* d_ws, size_t ws_size,
                              hipStream_t stream) {
    const float* x      = (const float*)d_in[0];
    const int*   ei     = (const int*)d_in[1];
    const int*   batch  = (const int*)d_in[2];
    const float* W1     = (const float*)d_in[3];
    const float* b1     = (const float*)d_in[4];
    const float* W2     = (const float*)d_in[5];
    const float* b2     = (const float*)d_in[6];
    const float* att_w  = (const float*)d_in[7];
    const float* att_b  = (const float*)d_in[8];
    const float* proj_w = (const float*)d_in[9];
    const float* proj_b = (const float*)d_in[10];
    const float* cls_w1 = (const float*)d_in[11];
    const float* cls_b1 = (const float*)d_in[12];
    const float* cls_w2 = (const float*)d_in[13];
    const float* cls_b2 = (const float*)d_in[14];
    float* out = (float*)d_out;

    const int* e_src = ei;
    const int* e_dst = ei + N_EDGES;

    // workspace layout (float words; all sizes multiples of 32 words -> 128B-aligned buffers)
    float* base = (float*)d_ws;
    size_t o = 0;
    float*    dis       = base + o;              o += 50048;
    int*      deg_i     = (int*)(base + o);      o += 50048;
    int*      row_start = (int*)(base + o);      o += 50080;   // N+1 used, padded
    int*      partials  = (int*)(base + o);      o += 256;
    unsigned* pk        = (unsigned*)(base + o); o += 800000;
    __half*   h1        = (__half*)(base + o);   o += 1600000; // 50000*64 fp16
    __half*   h2        = (__half*)(base + o);   o += 1600000;
    __half*   agg2      = (__half*)(base + o);   o += 1600000; // fp16 now
    int*      rank      = (int*)agg2;            // alias: rank (3.2MB) dead before agg2 written
    float*    att_s     = base + o;              o += 50048;
    int*      gs        = (int*)(base + o);      o += 512;
    int*      ge        = (int*)(base + o);      o += 512;
    __half*   W1T       = (__half*)(base + o);   o += 4096;    // 64x128 fp16
    __half*   W2T       = (__half*)(base + o);   o += 2048;    // 64x64 fp16

    const int NB_E  = (N_EDGES + 255) / 256;   // 3125
    const int NB_GG = N_NODES / 16;            // 3125 (exact)

    kA<<<244, 256, 0, stream>>>(deg_i, gs, ge, W1, W1T, W2, W2T);
    k_deg_rank<<<NB_E, 256, 0, stream>>>(e_dst, deg_i, rank);
    k_scan1<<<SCAN_BLOCKS, 256, 0, stream>>>(deg_i, row_start, partials, dis);
    k_scan3b<<<SCAN_BLOCKS, 256, 0, stream>>>(row_start, partials);

    // fill || gemm1 (independent, one launch)
    kB<<<NB_FILL + 782, 256, 0, stream>>>(e_src, e_dst, rank, row_start, dis, pk, x, W1T, h1);

    // conv1-aggregate + conv2-transform (MFMA)
    k_gg<<<NB_GG, 256, 0, stream>>>(h1, pk, row_start, dis, b1, W2T, h2);

    // conv2-aggregate + att score || gbounds
    kC<<<NB_G2 + SCAN_BLOCKS, 256, 0, stream>>>(h2, pk, row_start, dis, b2, att_w, att_b,
                                                agg2, att_s, batch, gs, ge);

    // pooling + head
    k_pool_head<<<N_GRAPHS, 256, 0, stream>>>(agg2, att_s, gs, ge,
                                              proj_w, proj_b, cls_w1, cls_b1,
                                              cls_w2, cls_b2, out);
}

// Round 11
// 157.263 us; speedup vs baseline: 1.2541x; 1.0413x over previous
//
#include <hip/hip_runtime.h>
#include <hip/hip_fp16.h>
#include <math.h>

#define N_NODES   50000
#define N_EDGES   800000
#define N_FEAT    128
#define HIDDEN    64
#define EMBED     300
#define N_CLASSES 10
#define N_GRAPHS  500
#define LEAKY     0.01f
#define SCAN_BLOCKS 196
#define NB_FILL   3125
#define NB_G2B    6250

typedef __attribute__((ext_vector_type(4))) _Float16 half4f;
typedef __attribute__((ext_vector_type(8))) _Float16 half8;
typedef __attribute__((ext_vector_type(4))) float f32x4;

__device__ __forceinline__ float pk_w(unsigned p) {
    return __half2float(__ushort_as_half((unsigned short)(p >> 16)));
}

// ---------------- kA: zero(deg,gs,ge,aggs) + W1T + W2T ----------------
__global__ void kA(int* deg, int* gs, int* ge, unsigned long long* aggs,
                   const float* __restrict__ W1, __half* __restrict__ W1T,
                   const float* __restrict__ W2, __half* __restrict__ W2T) {
    int bid = blockIdx.x, tid = threadIdx.x;
    if (bid < 196) {
        int i = bid * 256 + tid;
        if (i < N_NODES) deg[i] = 0;
        if (i < N_GRAPHS) { gs[i] = 0; ge[i] = 0; }
        if (bid == 0 && tid < SCAN_BLOCKS) aggs[tid] = 0ULL;
    } else if (bid < 228) {
        int idx = (bid - 196) * 256 + tid;            // 8192 = 128*64
        int n = idx >> 7, k = idx & 127;
        W1T[idx] = __float2half(W1[k * HIDDEN + n]);  // W1T[n][k]
    } else {
        int idx = (bid - 228) * 256 + tid;            // 4096 = 64*64
        int n = idx >> 6, k = idx & 63;
        W2T[idx] = __float2half(W2[k * HIDDEN + n]);  // W2T[n][k]
    }
}

// ---------------- degree count + per-edge rank ----------------
__global__ void k_deg_rank(const int* __restrict__ dst, int* deg, int* rank) {
    int e = blockIdx.x * 256 + threadIdx.x;
    if (e < N_EDGES) rank[e] = atomicAdd(&deg[dst[e]], 1);
}

// ---------------- single-pass scan (decoupled lookback), + dis ----------------
__global__ __launch_bounds__(256) void k_scan(const int* __restrict__ deg,
                                              int* __restrict__ row_start,
                                              unsigned long long* __restrict__ aggs,
                                              float* __restrict__ dis) {
    __shared__ int wsum[4];
    int bid = blockIdx.x, tid = threadIdx.x;
    int i = bid * 256 + tid;
    int v = (i < N_NODES) ? deg[i] : 0;
    int lane = tid & 63, wid = tid >> 6;
    int s = v;
    #pragma unroll
    for (int off = 1; off < 64; off <<= 1) {
        int t = __shfl_up(s, off, 64);
        if (lane >= off) s += t;
    }
    if (lane == 63) wsum[wid] = s;
    __syncthreads();
    int woff = 0;
    for (int w = 0; w < wid; ++w) woff += wsum[w];
    int total = wsum[0] + wsum[1] + wsum[2] + wsum[3];

    // publish own aggregate (ready bit | value)
    if (tid == 0)
        atomicExch(&aggs[bid], (1ULL << 32) | (unsigned long long)(unsigned)total);

    // lookback: thread t spins on aggs[t] for t < bid
    int pv = 0;
    if (tid < bid) {
        unsigned long long g;
        do { g = atomicAdd(&aggs[tid], 0ULL); } while (!(g >> 32));
        pv = (int)(unsigned)(g & 0xFFFFFFFFULL);
    }
    #pragma unroll
    for (int off = 32; off > 0; off >>= 1) pv += __shfl_xor(pv, off, 64);
    __syncthreads();               // protect wsum reuse
    if (lane == 0) wsum[wid] = pv;
    __syncthreads();
    int prefix = wsum[0] + wsum[1] + wsum[2] + wsum[3];

    if (i < N_NODES) {
        row_start[i] = woff + s - v + prefix;
        dis[i] = rsqrtf((float)(deg[i] + 1));
    }
    if (i == 0) row_start[N_NODES] = N_EDGES;
}

// ---------------- kB: CSR fill (0..3124) || MFMA gemm1 (3125..3906) ----------------
__global__ __launch_bounds__(256) void kB(const int* __restrict__ src, const int* __restrict__ dst,
                                          const int* __restrict__ rank, const int* __restrict__ row_start,
                                          const float* __restrict__ dis, unsigned* __restrict__ pk,
                                          const float* __restrict__ x, const __half* __restrict__ W1T,
                                          __half* __restrict__ h1) {
    if (blockIdx.x < NB_FILL) {
        int e = blockIdx.x * 256 + threadIdx.x;
        if (e < N_EDGES) {
            int s = src[e], d = dst[e];
            float w = dis[s] * dis[d];
            unsigned short wh = __half_as_ushort(__float2half(w));
            pk[row_start[d] + rank[e]] = (unsigned)s | ((unsigned)wh << 16);
        }
        return;
    }
    int tid = threadIdx.x, wid = tid >> 6, lane = tid & 63;
    int r16 = lane & 15, kg = lane >> 4;
    int rowbase = (blockIdx.x - NB_FILL) * 64 + wid * 16;
    int arow = rowbase + r16;
    bool avalid = arow < N_NODES;
    const float* xr = x + (size_t)arow * N_FEAT;

    half8 a[4];
    #pragma unroll
    for (int kt = 0; kt < 4; ++kt) {
        int k0 = kt * 32 + kg * 8;
        float4 u = avalid ? *(const float4*)(xr + k0)     : make_float4(0.f, 0.f, 0.f, 0.f);
        float4 v = avalid ? *(const float4*)(xr + k0 + 4) : make_float4(0.f, 0.f, 0.f, 0.f);
        a[kt][0] = (_Float16)u.x; a[kt][1] = (_Float16)u.y;
        a[kt][2] = (_Float16)u.z; a[kt][3] = (_Float16)u.w;
        a[kt][4] = (_Float16)v.x; a[kt][5] = (_Float16)v.y;
        a[kt][6] = (_Float16)v.z; a[kt][7] = (_Float16)v.w;
    }
    #pragma unroll
    for (int nt = 0; nt < 4; ++nt) {
        f32x4 acc = {0.f, 0.f, 0.f, 0.f};
        const _Float16* wp = (const _Float16*)W1T + (size_t)(nt * 16 + r16) * N_FEAT + kg * 8;
        #pragma unroll
        for (int kt = 0; kt < 4; ++kt) {
            half8 b = *(const half8*)(wp + kt * 32);
            acc = __builtin_amdgcn_mfma_f32_16x16x32_f16(a[kt], b, acc, 0, 0, 0);
        }
        int col = nt * 16 + r16;
        #pragma unroll
        for (int r = 0; r < 4; ++r) {
            int row = rowbase + kg * 4 + r;
            if (row < N_NODES) h1[(size_t)row * HIDDEN + col] = __float2half(acc[r]);
        }
    }
}

// ---------------- gather cores ----------------
__device__ __forceinline__ void gather4pk(const __half* __restrict__ h,
                                          const unsigned* __restrict__ pk,
                                          int s, int e, int lane, int g4, int q,
                                          float4& acc) {
    for (int cs = s; cs < e; cs += 64) {
        unsigned pkv = (cs + lane < e) ? pk[cs + lane] : 0u;
        int avail = e - cs; if (avail > 64) avail = 64;
        int iters = (avail + 3) >> 2;
        #pragma unroll 2
        for (int t = 0; t < iters; ++t) {
            unsigned p = __shfl(pkv, t * 4 + g4, 64);
            float w = pk_w(p);
            half4f hv = *(const half4f*)(h + ((size_t)(p & 0xFFFFu)) * HIDDEN + (q << 2));
            acc.x = fmaf(w, (float)hv.x, acc.x);
            acc.y = fmaf(w, (float)hv.y, acc.y);
            acc.z = fmaf(w, (float)hv.z, acc.z);
            acc.w = fmaf(w, (float)hv.w, acc.w);
        }
    }
}

// two nodes jointly: both pk loads in flight, interleaved row streams
__device__ __forceinline__ void gather2(const __half* __restrict__ h,
                                        const unsigned* __restrict__ pk,
                                        int s0, int e0, int s1, int e1,
                                        int lane, int g4, int q,
                                        float4& a0, float4& a1) {
    unsigned pv0 = (s0 + lane < e0) ? pk[s0 + lane] : 0u;
    unsigned pv1 = (s1 + lane < e1) ? pk[s1 + lane] : 0u;
    int n0 = e0 - s0; if (n0 > 64) n0 = 64; if (n0 < 0) n0 = 0;
    int n1 = e1 - s1; if (n1 > 64) n1 = 64; if (n1 < 0) n1 = 0;
    int it0 = (n0 + 3) >> 2, it1 = (n1 + 3) >> 2;
    int itm = it0 > it1 ? it0 : it1;
    for (int t = 0; t < itm; ++t) {
        if (t < it0) {
            unsigned p = __shfl(pv0, t * 4 + g4, 64);
            float w = pk_w(p);
            half4f hv = *(const half4f*)(h + ((size_t)(p & 0xFFFFu)) * HIDDEN + (q << 2));
            a0.x = fmaf(w, (float)hv.x, a0.x);
            a0.y = fmaf(w, (float)hv.y, a0.y);
            a0.z = fmaf(w, (float)hv.z, a0.z);
            a0.w = fmaf(w, (float)hv.w, a0.w);
        }
        if (t < it1) {
            unsigned p = __shfl(pv1, t * 4 + g4, 64);
            float w = pk_w(p);
            half4f hv = *(const half4f*)(h + ((size_t)(p & 0xFFFFu)) * HIDDEN + (q << 2));
            a1.x = fmaf(w, (float)hv.x, a1.x);
            a1.y = fmaf(w, (float)hv.y, a1.y);
            a1.z = fmaf(w, (float)hv.z, a1.z);
            a1.w = fmaf(w, (float)hv.w, a1.w);
        }
    }
    if (e0 - s0 > 64) gather4pk(h, pk, s0 + 64, e0, lane, g4, q, a0);
    if (e1 - s1 > 64) gather4pk(h, pk, s1 + 64, e1, lane, g4, q, a1);
}

__device__ __forceinline__ void xreduce(float4& a) {
    a.x += __shfl_xor(a.x, 16, 64); a.y += __shfl_xor(a.y, 16, 64);
    a.z += __shfl_xor(a.z, 16, 64); a.w += __shfl_xor(a.w, 16, 64);
    a.x += __shfl_xor(a.x, 32, 64); a.y += __shfl_xor(a.y, 32, 64);
    a.z += __shfl_xor(a.z, 32, 64); a.w += __shfl_xor(a.w, 32, 64);
}

// ---------------- k_gg: conv1-gather (2-node pairs) + MFMA gemm2, 16 nodes/block ----------------
__global__ __launch_bounds__(256) void k_gg(const __half* __restrict__ h1,
                                            const unsigned* __restrict__ pk,
                                            const int* __restrict__ row_start,
                                            const float* __restrict__ dis,
                                            const float* __restrict__ b1,
                                            const __half* __restrict__ W2T,
                                            __half* __restrict__ h2) {
    __shared__ __align__(16) __half sa[16 * 72];   // stride 72 halves = 144B
    int tid = threadIdx.x, wid = tid >> 6, lane = tid & 63;
    int g4 = lane >> 4, q = lane & 15;
    int base = blockIdx.x * 16 + wid * 4;   // 50000 = 3125*16
    float4 bv = *(const float4*)(b1 + (q << 2));

    #pragma unroll
    for (int pr = 0; pr < 2; ++pr) {
        int n0 = base + pr * 2, n1 = n0 + 1;
        int s0 = row_start[n0], e0 = row_start[n0 + 1];
        int s1 = row_start[n1], e1 = row_start[n1 + 1];
        float4 a0 = {0.f, 0.f, 0.f, 0.f}, a1 = {0.f, 0.f, 0.f, 0.f};
        gather2(h1, pk, s0, e0, s1, e1, lane, g4, q, a0, a1);
        xreduce(a0); xreduce(a1);
        if (g4 == 0) {
            float d0 = dis[n0]; d0 *= d0;
            float d1 = dis[n1]; d1 *= d1;
            half4f sv0 = *(const half4f*)(h1 + (size_t)n0 * HIDDEN + (q << 2));
            half4f sv1 = *(const half4f*)(h1 + (size_t)n1 * HIDDEN + (q << 2));
            half4f r0, r1;
            r0.x = (_Float16)fmaxf(fmaf((float)sv0.x, d0, bv.x) + a0.x, 0.f);
            r0.y = (_Float16)fmaxf(fmaf((float)sv0.y, d0, bv.y) + a0.y, 0.f);
            r0.z = (_Float16)fmaxf(fmaf((float)sv0.z, d0, bv.z) + a0.z, 0.f);
            r0.w = (_Float16)fmaxf(fmaf((float)sv0.w, d0, bv.w) + a0.w, 0.f);
            r1.x = (_Float16)fmaxf(fmaf((float)sv1.x, d1, bv.x) + a1.x, 0.f);
            r1.y = (_Float16)fmaxf(fmaf((float)sv1.y, d1, bv.y) + a1.y, 0.f);
            r1.z = (_Float16)fmaxf(fmaf((float)sv1.z, d1, bv.z) + a1.z, 0.f);
            r1.w = (_Float16)fmaxf(fmaf((float)sv1.w, d1, bv.w) + a1.w, 0.f);
            *(half4f*)&sa[(wid * 4 + pr * 2 + 0) * 72 + (q << 2)] = r0;
            *(half4f*)&sa[(wid * 4 + pr * 2 + 1) * 72 + (q << 2)] = r1;
        }
    }
    __syncthreads();

    // MFMA: D[16 nodes][64 cols]; wave wid does col-tile [wid*16, wid*16+16)
    int r16 = lane & 15, kg = lane >> 4;
    f32x4 acc = {0.f, 0.f, 0.f, 0.f};
    const _Float16* wp = (const _Float16*)W2T + (size_t)(wid * 16 + r16) * HIDDEN + kg * 8;
    #pragma unroll
    for (int kt = 0; kt < 2; ++kt) {
        half8 a = *(const half8*)&sa[r16 * 72 + kt * 32 + kg * 8];
        half8 b = *(const half8*)(wp + kt * 32);
        acc = __builtin_amdgcn_mfma_f32_16x16x32_f16(a, b, acc, 0, 0, 0);
    }
    int col = wid * 16 + r16;
    int nodebase = blockIdx.x * 16;
    #pragma unroll
    for (int r = 0; r < 4; ++r) {
        int row = nodebase + kg * 4 + r;
        h2[(size_t)row * HIDDEN + col] = __float2half(acc[r]);
    }
}

// ---------------- kC: conv2-gather 2-node/wave + att (0..6249) || gbounds (6250..) ----------------
__global__ __launch_bounds__(256) void kC(const __half* __restrict__ h2,
                                          const unsigned* __restrict__ pk,
                                          const int* __restrict__ row_start,
                                          const float* __restrict__ dis,
                                          const float* __restrict__ b2,
                                          const float* __restrict__ att_w,
                                          const float* __restrict__ att_b,
                                          __half* __restrict__ agg2,
                                          float* __restrict__ att_s,
                                          const int* __restrict__ batch,
                                          int* gs, int* ge) {
    if (blockIdx.x >= NB_G2B) {
        int n = (blockIdx.x - NB_G2B) * 256 + threadIdx.x;
        if (n < N_NODES) {
            int b = batch[n];
            if (n == 0 || batch[n - 1] != b) gs[b] = n;
            if (n == N_NODES - 1 || batch[n + 1] != b) ge[b] = n + 1;
        }
        return;
    }
    int tid = threadIdx.x, wid = tid >> 6, lane = tid & 63;
    int g4 = lane >> 4, q = lane & 15;
    int n0 = blockIdx.x * 8 + wid * 2, n1 = n0 + 1;   // 6250*8 = 50000 exact
    int s0 = row_start[n0], e0 = row_start[n0 + 1];
    int s1 = row_start[n1], e1 = row_start[n1 + 1];
    float4 a0 = {0.f, 0.f, 0.f, 0.f}, a1 = {0.f, 0.f, 0.f, 0.f};
    gather2(h2, pk, s0, e0, s1, e1, lane, g4, q, a0, a1);
    xreduce(a0); xreduce(a1);

    float4 bv = *(const float4*)(b2 + (q << 2));
    float d0 = dis[n0]; d0 *= d0;
    float d1 = dis[n1]; d1 *= d1;
    half4f sv0 = *(const half4f*)(h2 + (size_t)n0 * HIDDEN + (q << 2));
    half4f sv1 = *(const half4f*)(h2 + (size_t)n1 * HIDDEN + (q << 2));
    float4 r0, r1;
    r0.x = fmaxf(fmaf((float)sv0.x, d0, bv.x) + a0.x, 0.f);
    r0.y = fmaxf(fmaf((float)sv0.y, d0, bv.y) + a0.y, 0.f);
    r0.z = fmaxf(fmaf((float)sv0.z, d0, bv.z) + a0.z, 0.f);
    r0.w = fmaxf(fmaf((float)sv0.w, d0, bv.w) + a0.w, 0.f);
    r1.x = fmaxf(fmaf((float)sv1.x, d1, bv.x) + a1.x, 0.f);
    r1.y = fmaxf(fmaf((float)sv1.y, d1, bv.y) + a1.y, 0.f);
    r1.z = fmaxf(fmaf((float)sv1.z, d1, bv.z) + a1.z, 0.f);
    r1.w = fmaxf(fmaf((float)sv1.w, d1, bv.w) + a1.w, 0.f);
    if (g4 == 0) {
        half4f h0, h1v;
        h0.x = (_Float16)r0.x; h0.y = (_Float16)r0.y; h0.z = (_Float16)r0.z; h0.w = (_Float16)r0.w;
        h1v.x = (_Float16)r1.x; h1v.y = (_Float16)r1.y; h1v.z = (_Float16)r1.z; h1v.w = (_Float16)r1.w;
        *(half4f*)(agg2 + (size_t)n0 * HIDDEN + (q << 2)) = h0;
        *(half4f*)(agg2 + (size_t)n1 * HIDDEN + (q << 2)) = h1v;
    }

    float4 aw = *(const float4*)(att_w + (q << 2));
    float v0 = fmaf(r0.x, aw.x, fmaf(r0.y, aw.y, fmaf(r0.z, aw.z, r0.w * aw.w)));
    float v1 = fmaf(r1.x, aw.x, fmaf(r1.y, aw.y, fmaf(r1.z, aw.z, r1.w * aw.w)));
    v0 += __shfl_xor(v0, 1, 64); v1 += __shfl_xor(v1, 1, 64);
    v0 += __shfl_xor(v0, 2, 64); v1 += __shfl_xor(v1, 2, 64);
    v0 += __shfl_xor(v0, 4, 64); v1 += __shfl_xor(v1, 4, 64);
    v0 += __shfl_xor(v0, 8, 64); v1 += __shfl_xor(v1, 8, 64);
    if (lane == 0) {
        float sc0 = v0 + att_b[0];
        float sc1 = v1 + att_b[0];
        att_s[n0] = (sc0 > 0.0f) ? sc0 : LEAKY * sc0;
        att_s[n1] = (sc1 > 0.0f) ? sc1 : LEAKY * sc1;
    }
}

// ---------------- fused pool + head MLPs ----------------
__global__ __launch_bounds__(256) void k_pool_head(const __half* __restrict__ agg2,
                                                   const float* __restrict__ att_s,
                                                   const int* __restrict__ gs,
                                                   const int* __restrict__ ge,
                                                   const float* __restrict__ proj_w,
                                                   const float* __restrict__ proj_b,
                                                   const float* __restrict__ cls_w1,
                                                   const float* __restrict__ cls_b1,
                                                   const float* __restrict__ cls_w2,
                                                   const float* __restrict__ cls_b2,
                                                   float* __restrict__ out) {
    __shared__ float red[4];
    __shared__ float red2[4 * 64];
    __shared__ float sG[HIDDEN];
    __shared__ float sT1[EMBED];
    __shared__ float sT2[128];
    int gid = blockIdx.x;
    int tid = threadIdx.x, f = tid & 63, w = tid >> 6;
    int s = gs[gid], e = ge[gid];

    float m = -INFINITY;
    for (int n = s + tid; n < e; n += 256) m = fmaxf(m, att_s[n]);
    #pragma unroll
    for (int o = 32; o > 0; o >>= 1) m = fmaxf(m, __shfl_xor(m, o, 64));
    if (f == 0) red[w] = m;
    __syncthreads();
    m = fmaxf(fmaxf(red[0], red[1]), fmaxf(red[2], red[3]));
    __syncthreads();

    float z = 0.0f;
    for (int n = s + tid; n < e; n += 256) z += expf(att_s[n] - m);
    #pragma unroll
    for (int o = 32; o > 0; o >>= 1) z += __shfl_xor(z, o, 64);
    if (f == 0) red[w] = z;
    __syncthreads();
    z = red[0] + red[1] + red[2] + red[3];
    float inv = (e > s) ? 1.0f / z : 0.0f;

    float acc = 0.0f;
    for (int n = s + w; n < e; n += 4)
        acc = fmaf(expf(att_s[n] - m) * inv,
                   __half2float(agg2[(size_t)n * HIDDEN + f]), acc);
    red2[w * 64 + f] = acc;
    __syncthreads();
    if (w == 0) sG[f] = red2[f] + red2[64 + f] + red2[128 + f] + red2[192 + f];
    __syncthreads();

    for (int c = tid; c < EMBED; c += 256) {
        float a = proj_b[c];
        #pragma unroll 8
        for (int k = 0; k < HIDDEN; ++k) a = fmaf(sG[k], proj_w[k * EMBED + c], a);
        sT1[c] = a;
    }
    __syncthreads();

    if (tid < 128) {
        float a = cls_b1[tid];
        for (int k = 0; k < EMBED; ++k) a = fmaf(sT1[k], cls_w1[k * 128 + tid], a);
        sT2[tid] = fmaxf(a, 0.f);
    }
    __syncthreads();

    if (tid < N_CLASSES) {
        float a = cls_b2[tid];
        #pragma unroll 8
        for (int k = 0; k < 128; ++k) a = fmaf(sT2[k], cls_w2[k * N_CLASSES + tid], a);
        out[gid * N_CLASSES + tid] = a;
    }
}

extern "C" void kernel_launch(void* const* d_in, const int* in_sizes, int n_in,
                              void* d_out, int out_size, void* d_ws, size_t ws_size,
                              hipStream_t stream) {
    const float* x      = (const float*)d_in[0];
    const int*   ei     = (const int*)d_in[1];
    const int*   batch  = (const int*)d_in[2];
    const float* W1     = (const float*)d_in[3];
    const float* b1     = (const float*)d_in[4];
    const float* W2     = (const float*)d_in[5];
    const float* b2     = (const float*)d_in[6];
    const float* att_w  = (const float*)d_in[7];
    const float* att_b  = (const float*)d_in[8];
    const float* proj_w = (const float*)d_in[9];
    const float* proj_b = (const float*)d_in[10];
    const float* cls_w1 = (const float*)d_in[11];
    const float* cls_b1 = (const float*)d_in[12];
    const float* cls_w2 = (const float*)d_in[13];
    const float* cls_b2 = (const float*)d_in[14];
    float* out = (float*)d_out;

    const int* e_src = ei;
    const int* e_dst = ei + N_EDGES;

    // workspace (float words; all offsets multiples of 32 -> 128B-aligned)
    float* base = (float*)d_ws;
    size_t o = 0;
    float*    dis       = base + o;              o += 50048;
    int*      deg_i     = (int*)(base + o);      o += 50048;
    int*      row_start = (int*)(base + o);      o += 50080;
    unsigned long long* aggs = (unsigned long long*)(base + o); o += 512;
    unsigned* pk        = (unsigned*)(base + o); o += 800000;
    __half*   h1        = (__half*)(base + o);   o += 1600000;
    __half*   h2        = (__half*)(base + o);   o += 1600000;
    __half*   agg2      = (__half*)(base + o);   o += 1600000;
    int*      rank      = (int*)agg2;            // alias: rank dead before agg2 written
    float*    att_s     = base + o;              o += 50048;
    int*      gs        = (int*)(base + o);      o += 512;
    int*      ge        = (int*)(base + o);      o += 512;
    __half*   W1T       = (__half*)(base + o);   o += 4096;
    __half*   W2T       = (__half*)(base + o);   o += 2048;

    const int NB_E  = (N_EDGES + 255) / 256;   // 3125
    const int NB_GG = N_NODES / 16;            // 3125

    kA<<<244, 256, 0, stream>>>(deg_i, gs, ge, aggs, W1, W1T, W2, W2T);
    k_deg_rank<<<NB_E, 256, 0, stream>>>(e_dst, deg_i, rank);
    k_scan<<<SCAN_BLOCKS, 256, 0, stream>>>(deg_i, row_start, aggs, dis);

    // fill || gemm1
    kB<<<NB_FILL + 782, 256, 0, stream>>>(e_src, e_dst, rank, row_start, dis, pk, x, W1T, h1);

    // conv1-aggregate + conv2-transform
    k_gg<<<NB_GG, 256, 0, stream>>>(h1, pk, row_start, dis, b1, W2T, h2);

    // conv2-aggregate + att || gbounds
    kC<<<NB_G2B + SCAN_BLOCKS, 256, 0, stream>>>(h2, pk, row_start, dis, b2, att_w, att_b,
                                                 agg2, att_s, batch, gs, ge);

    // pooling + head
    k_pool_head<<<N_GRAPHS, 256, 0, stream>>>(agg2, att_s, gs, ge,
                                              proj_w, proj_b, cls_w1, cls_b1,
                                              cls_w2, cls_b2, out);
}